// Round 5
// baseline (2120.957 us; speedup 1.0000x reference)
//
#include <hip/hip_runtime.h>
#include <cstdint>

// Shapes
#define BB 2
#define HH_ 256
#define WW_ 256
#define CC 96
#define NTOK 65536           // H*W
#define MTOK 131072          // B*N
#define HEADS 6
#define WS 16
#define WSQ 256
#define HEAD_D 16
#define TOPK 64
#define HID 12
#define MLP_ 192

typedef short v8s __attribute__((ext_vector_type(8)));
typedef float v4f __attribute__((ext_vector_type(4)));

__device__ __forceinline__ float gelu_f(float v) {
  return 0.5f * v * (1.0f + erff(v * 0.70710678118654752440f));
}
__device__ __forceinline__ float lrelu_f(float v) { return v >= 0.0f ? v : 0.2f * v; }
__device__ __forceinline__ unsigned short bf16r(float f) {
  unsigned u = __float_as_uint(f);
  unsigned r = u + 0x7fffu + ((u >> 16) & 1u);
  return (unsigned short)(r >> 16);
}
__device__ __forceinline__ float bf16d(unsigned short h) {
  return __uint_as_float(((unsigned)h) << 16);
}

// ---------------- LayerNorm over C=96: one wave per token ----------------
__global__ __launch_bounds__(256) void ln_kernel(const float* __restrict__ in,
    const float* __restrict__ gam, const float* __restrict__ bet, float* __restrict__ out) {
  int wid = blockIdx.x * 4 + (threadIdx.x >> 6);
  int lane = threadIdx.x & 63;
  const float* row = in + (size_t)wid * CC;
  float v0 = row[lane];
  float v1 = (lane < 32) ? row[64 + lane] : 0.0f;
  float s = v0 + v1;
  #pragma unroll
  for (int off = 32; off; off >>= 1) s += __shfl_xor(s, off);
  float mean = s * (1.0f / 96.0f);
  float d0 = v0 - mean;
  float d1 = (lane < 32) ? (v1 - mean) : 0.0f;
  float q = d0 * d0 + d1 * d1;
  #pragma unroll
  for (int off = 32; off; off >>= 1) q += __shfl_xor(q, off);
  float r = rsqrtf(q * (1.0f / 96.0f) + 1e-5f);
  float* orow = out + (size_t)wid * CC;
  orow[lane] = d0 * r * gam[lane] + bet[lane];
  if (lane < 32) orow[64 + lane] = d1 * r * gam[64 + lane] + bet[64 + lane];
}

// ---------------- Global average pool ----------------
__global__ __launch_bounds__(128) void pool_kernel(const float* __restrict__ A, float* __restrict__ pooled) {
  int c = threadIdx.x;
  if (c >= CC) return;
  int b = blockIdx.y;
  int t0 = blockIdx.x * 512;
  const float* base = A + ((size_t)b * NTOK + t0) * CC + c;
  float acc = 0.0f;
  #pragma unroll 8
  for (int t = 0; t < 512; t++) acc += base[(size_t)t * CC];
  atomicAdd(&pooled[b * CC + c], acc);
}

// ---------------- Gate MLP ----------------
__global__ __launch_bounds__(64) void gate_kernel(const float* __restrict__ pooled,
    const float* __restrict__ w1, const float* __restrict__ b1,
    const float* __restrict__ w2, const float* __restrict__ b2, float* __restrict__ gv) {
  __shared__ float hb[BB][HID];
  __shared__ float lb[BB][3];
  int tid = threadIdx.x;
  if (tid < BB * HID) {
    int b = tid / HID, o = tid % HID;
    float s = b1[o];
    for (int c = 0; c < CC; c++) s += (pooled[b * CC + c] * (1.0f / 65536.0f)) * w1[o * CC + c];
    hb[b][o] = fmaxf(s, 0.0f);
  }
  __syncthreads();
  if (tid < BB * 3) {
    int b = tid / 3, j = tid % 3;
    float s = b2[j];
    for (int o = 0; o < HID; o++) s += hb[b][o] * w2[j * HID + o];
    lb[b][j] = s;
  }
  __syncthreads();
  if (tid < BB) {
    float m = fmaxf(lb[tid][0], fmaxf(lb[tid][1], lb[tid][2]));
    float e0 = __expf(lb[tid][0] - m), e1 = __expf(lb[tid][1] - m), e2 = __expf(lb[tid][2] - m);
    float inv = 1.0f / (e0 + e1 + e2);
    gv[tid * 3 + 0] = e0 * inv; gv[tid * 3 + 1] = e1 * inv; gv[tid * 3 + 2] = e2 * inv;
  }
}

// ---------------- MFMA GEMM: out[p,o] = act(sum_c A[p,c]*W[o,c] + b[o]) (+resid) -------
template <int K, int NO, int ACT, bool RESID, bool HASB>
__global__ __launch_bounds__(256, 4) void mgemm_kernel(const float* __restrict__ A,
    const float* __restrict__ W, const float* __restrict__ bias,
    const float* __restrict__ resid, float* __restrict__ out, int ostride, int rstride) {
  __shared__ __align__(16) unsigned short al[128][104];  // stride 52 dw == 4 mod 8
  __shared__ __align__(16) unsigned short wl[64][104];
  int tid = threadIdx.x;
  int lane = tid & 63, wv = tid >> 6, quad = lane >> 4, to = lane & 15;
  int o0 = blockIdx.x * 64, p0 = blockIdx.y * 128;
  v4f acc[2][4];
  #pragma unroll
  for (int ni = 0; ni < 4; ni++) {
    float bv = 0.0f;
    if (HASB) { int o = o0 + ni * 16 + to; if (o < NO) bv = bias[o]; }
    #pragma unroll
    for (int mi = 0; mi < 2; mi++) acc[mi][ni] = (v4f){bv, bv, bv, bv};
  }
  for (int kc = 0; kc < K; kc += 96) {
    __syncthreads();
    {
      int r = tid & 127, half = tid >> 7;
      const float* ap = A + (size_t)(p0 + r) * K + kc + half * 48;
      #pragma unroll
      for (int g = 0; g < 3; g++) {
        float4 f0 = *(const float4*)(ap + g * 16);
        float4 f1 = *(const float4*)(ap + g * 16 + 4);
        float4 f2 = *(const float4*)(ap + g * 16 + 8);
        float4 f3 = *(const float4*)(ap + g * 16 + 12);
        uint4 u, v;
        u.x = (unsigned)bf16r(f0.x) | ((unsigned)bf16r(f0.y) << 16);
        u.y = (unsigned)bf16r(f0.z) | ((unsigned)bf16r(f0.w) << 16);
        u.z = (unsigned)bf16r(f1.x) | ((unsigned)bf16r(f1.y) << 16);
        u.w = (unsigned)bf16r(f1.z) | ((unsigned)bf16r(f1.w) << 16);
        v.x = (unsigned)bf16r(f2.x) | ((unsigned)bf16r(f2.y) << 16);
        v.y = (unsigned)bf16r(f2.z) | ((unsigned)bf16r(f2.w) << 16);
        v.z = (unsigned)bf16r(f3.x) | ((unsigned)bf16r(f3.y) << 16);
        v.w = (unsigned)bf16r(f3.z) | ((unsigned)bf16r(f3.w) << 16);
        *(uint4*)&al[r][half * 48 + g * 16] = u;
        *(uint4*)&al[r][half * 48 + g * 16 + 8] = v;
      }
    }
    {
      int r = tid & 63, q = tid >> 6;
      int o = o0 + r;
      if (o < NO) {
        const float* wp = W + (size_t)o * K + kc + q * 24;
        #pragma unroll
        for (int g = 0; g < 3; g++) {
          float4 f0 = *(const float4*)(wp + g * 8);
          float4 f1 = *(const float4*)(wp + g * 8 + 4);
          uint4 u;
          u.x = (unsigned)bf16r(f0.x) | ((unsigned)bf16r(f0.y) << 16);
          u.y = (unsigned)bf16r(f0.z) | ((unsigned)bf16r(f0.w) << 16);
          u.z = (unsigned)bf16r(f1.x) | ((unsigned)bf16r(f1.y) << 16);
          u.w = (unsigned)bf16r(f1.z) | ((unsigned)bf16r(f1.w) << 16);
          *(uint4*)&wl[r][q * 24 + g * 8] = u;
        }
      } else {
        uint4 z = make_uint4(0, 0, 0, 0);
        #pragma unroll
        for (int g = 0; g < 3; g++) *(uint4*)&wl[r][q * 24 + g * 8] = z;
      }
    }
    __syncthreads();
    #pragma unroll
    for (int ks = 0; ks < 3; ks++) {
      v8s af[2], bfr[4];
      #pragma unroll
      for (int mi = 0; mi < 2; mi++)
        af[mi] = *(const v8s*)&al[wv * 32 + mi * 16 + to][ks * 32 + quad * 8];
      #pragma unroll
      for (int ni = 0; ni < 4; ni++)
        bfr[ni] = *(const v8s*)&wl[ni * 16 + to][ks * 32 + quad * 8];
      #pragma unroll
      for (int mi = 0; mi < 2; mi++)
        #pragma unroll
        for (int ni = 0; ni < 4; ni++)
          acc[mi][ni] = __builtin_amdgcn_mfma_f32_16x16x32_bf16(af[mi], bfr[ni], acc[mi][ni], 0, 0, 0);
    }
  }
  #pragma unroll
  for (int mi = 0; mi < 2; mi++)
    #pragma unroll
    for (int ni = 0; ni < 4; ni++) {
      int o = o0 + ni * 16 + to;
      if (o < NO) {
        #pragma unroll
        for (int rg = 0; rg < 4; rg++) {
          int p = p0 + wv * 32 + mi * 16 + quad * 4 + rg;
          float v = acc[mi][ni][rg];
          if (ACT == 1) v = lrelu_f(v);
          else if (ACT == 2) v = gelu_f(v);
          if (RESID) v += resid[(size_t)p * rstride + o];
          out[(size_t)p * ostride + o] = v;
        }
      }
    }
}

// ---------------- Vector GEMM (small K; used for 12x12 pw) ----------------
template <int K, int KC, int NO, int ACT, bool RESID, bool HASB>
__global__ __launch_bounds__(256) void gemm_kernel(const float* __restrict__ in,
    const float* __restrict__ w, const float* __restrict__ bias,
    const float* __restrict__ resid, float* __restrict__ out, int ostride, int rstride) {
  __shared__ __align__(16) float xs[64][KC + 4];
  __shared__ __align__(16) float ws[64][KC + 4];
  int tid = threadIdx.x;
  int p0 = blockIdx.x * 64;
  int o0 = blockIdx.y * 64;
  int to = tid & 15, tp = tid >> 4;
  float acc[4][4];
  #pragma unroll
  for (int j = 0; j < 4; j++) {
    float bv = 0.0f;
    if (HASB) { int o = o0 + to + 16 * j; if (o < NO) bv = bias[o]; }
    #pragma unroll
    for (int i = 0; i < 4; i++) acc[i][j] = bv;
  }
  for (int kc = 0; kc < K; kc += KC) {
    __syncthreads();
    for (int idx = tid; idx < 64 * (KC / 4); idx += 256) {
      int p = idx / (KC / 4), c4 = idx % (KC / 4);
      *(float4*)&xs[p][c4 * 4] = *(const float4*)&in[(size_t)(p0 + p) * K + kc + c4 * 4];
    }
    for (int idx = tid; idx < 64 * (KC / 4); idx += 256) {
      int r = idx / (KC / 4), c4 = idx % (KC / 4);
      int o = o0 + r;
      float4 v = make_float4(0.f, 0.f, 0.f, 0.f);
      if (o < NO) v = *(const float4*)&w[(size_t)o * K + kc + c4 * 4];
      *(float4*)&ws[r][c4 * 4] = v;
    }
    __syncthreads();
    #pragma unroll 4
    for (int cc = 0; cc < KC; cc += 4) {
      float4 xv[4], wv[4];
      #pragma unroll
      for (int i = 0; i < 4; i++) xv[i] = *(const float4*)&xs[tp + 16 * i][cc];
      #pragma unroll
      for (int j = 0; j < 4; j++) wv[j] = *(const float4*)&ws[to + 16 * j][cc];
      #pragma unroll
      for (int i = 0; i < 4; i++)
        #pragma unroll
        for (int j = 0; j < 4; j++)
          acc[i][j] += xv[i].x * wv[j].x + xv[i].y * wv[j].y + xv[i].z * wv[j].z + xv[i].w * wv[j].w;
    }
  }
  #pragma unroll
  for (int i = 0; i < 4; i++) {
    int p = p0 + tp + 16 * i;
    #pragma unroll
    for (int j = 0; j < 4; j++) {
      int o = o0 + to + 16 * j;
      if (o < NO) {
        float v = acc[i][j];
        if (ACT == 1) v = lrelu_f(v);
        else if (ACT == 2) v = gelu_f(v);
        if (RESID) v += resid[(size_t)p * rstride + o];
        out[(size_t)p * ostride + o] = v;
      }
    }
  }
}

// ---------------- Depthwise KxK conv (NHWC), float4 over channels ----------------
template <int KSZ, int CH, int ACT, bool RESID>
__global__ __launch_bounds__(256) void dwconv_kernel(const float* __restrict__ in,
    const float* __restrict__ wt, const float* __restrict__ wb,
    const float* __restrict__ resid, float* __restrict__ out,
    int istride, int ostride, int rstride) {
  constexpr int C4 = CH / 4;
  constexpr int K2 = KSZ * KSZ;
  int e = blockIdx.x * 256 + threadIdx.x;
  int c4 = e % C4;
  int pix = e / C4;
  int b = pix >> 16, n = pix & 65535, h = n >> 8, w = n & 255;
  const int P = (KSZ - 1) / 2;
  int c = c4 * 4;
  float4 acc = *(const float4*)(wb + c);
  #pragma unroll
  for (int ky = 0; ky < KSZ; ky++) {
    int hh = h + ky - P;
    if (hh < 0 || hh >= HH_) continue;
    #pragma unroll
    for (int kx = 0; kx < KSZ; kx++) {
      int ww = w + kx - P;
      if (ww < 0 || ww >= WW_) continue;
      float4 iv = *(const float4*)(in + ((size_t)(b << 16) + (hh << 8) + ww) * istride + c);
      int t = ky * KSZ + kx;
      acc.x += wt[(c + 0) * K2 + t] * iv.x;
      acc.y += wt[(c + 1) * K2 + t] * iv.y;
      acc.z += wt[(c + 2) * K2 + t] * iv.z;
      acc.w += wt[(c + 3) * K2 + t] * iv.w;
    }
  }
  if (ACT == 1) {
    acc.x = lrelu_f(acc.x); acc.y = lrelu_f(acc.y); acc.z = lrelu_f(acc.z); acc.w = lrelu_f(acc.w);
  } else if (ACT == 2) {
    acc.x = gelu_f(acc.x); acc.y = gelu_f(acc.y); acc.z = gelu_f(acc.z); acc.w = gelu_f(acc.w);
  }
  if (RESID) {
    float4 rv = *(const float4*)(resid + (size_t)pix * rstride + c);
    acc.x += rv.x; acc.y += rv.y; acc.z += rv.z; acc.w += rv.w;
  }
  *(float4*)(out + (size_t)pix * ostride + c) = acc;
}

// ---------------- Depthwise 4-pixel conv: register reuse along W ----------------
template <int KSZ, int CH, int ACT, bool RESID>
__global__ __launch_bounds__(256) void dwconv4_kernel(const float* __restrict__ in,
    const float* __restrict__ wt, const float* __restrict__ wb,
    const float* __restrict__ resid, float* __restrict__ out,
    int istride, int ostride, int rstride) {
  constexpr int C4 = CH / 4;
  constexpr int K2 = KSZ * KSZ;
  constexpr int P = (KSZ - 1) / 2;
  constexpr int NC = KSZ + 3;
  int e = blockIdx.x * 256 + threadIdx.x;
  int c4 = e % C4;
  int g = e / C4;                     // pixel-group: b*16384 + h*64 + w0/4
  int b = g >> 14, rem = g & 16383, h = rem >> 6, w0 = (rem & 63) << 2;
  int c = c4 * 4;
  float4 wbv = *(const float4*)(wb + c);
  float4 acc[4] = {wbv, wbv, wbv, wbv};
  #pragma unroll
  for (int ky = 0; ky < KSZ; ky++) {
    int hh = h + ky - P;
    if (hh < 0 || hh >= HH_) continue;
    const float* rowp = in + ((size_t)(b << 16) + (hh << 8)) * istride + c;
    float4 iv[NC];
    #pragma unroll
    for (int k = 0; k < NC; k++) {
      int ww = w0 - P + k;
      if (ww >= 0 && ww < WW_) iv[k] = *(const float4*)(rowp + (size_t)ww * istride);
      else iv[k] = make_float4(0.f, 0.f, 0.f, 0.f);
    }
    #pragma unroll
    for (int kx = 0; kx < KSZ; kx++) {
      int t = ky * KSZ + kx;
      float wt0 = wt[(c + 0) * K2 + t];
      float wt1 = wt[(c + 1) * K2 + t];
      float wt2 = wt[(c + 2) * K2 + t];
      float wt3 = wt[(c + 3) * K2 + t];
      #pragma unroll
      for (int px = 0; px < 4; px++) {
        acc[px].x += wt0 * iv[kx + px].x;
        acc[px].y += wt1 * iv[kx + px].y;
        acc[px].z += wt2 * iv[kx + px].z;
        acc[px].w += wt3 * iv[kx + px].w;
      }
    }
  }
  #pragma unroll
  for (int px = 0; px < 4; px++) {
    float4 a = acc[px];
    if (ACT == 1) {
      a.x = lrelu_f(a.x); a.y = lrelu_f(a.y); a.z = lrelu_f(a.z); a.w = lrelu_f(a.w);
    } else if (ACT == 2) {
      a.x = gelu_f(a.x); a.y = gelu_f(a.y); a.z = gelu_f(a.z); a.w = gelu_f(a.w);
    }
    size_t pix = (size_t)(b << 16) + (h << 8) + w0 + px;
    if (RESID) {
      float4 rv = *(const float4*)(resid + pix * rstride + c);
      a.x += rv.x; a.y += rv.y; a.z += rv.z; a.w += rv.w;
    }
    *(float4*)(out + pix * ostride + c) = a;
  }
}

// ---------------- MoE combine (float4 over channels) ----------------
__global__ __launch_bounds__(256) void moe_combine_kernel(float* __restrict__ A,
    const float* __restrict__ t3a, const float* __restrict__ t3b, const float* __restrict__ t3c,
    const float* __restrict__ w2a, const float* __restrict__ w2b, const float* __restrict__ w2c,
    const float* __restrict__ b2a, const float* __restrict__ b2b, const float* __restrict__ b2c,
    const float* __restrict__ gv, const float* __restrict__ ms) {
  int e4 = blockIdx.x * 256 + threadIdx.x;
  int c4 = e4 % (CC / 4), pix = e4 / (CC / 4), b = pix >> 16;
  int c = c4 * 4;
  float4 sa = *(const float4*)(b2a + c);
  float4 sb = *(const float4*)(b2b + c);
  float4 sc = *(const float4*)(b2c + c);
  #pragma unroll
  for (int h2 = 0; h2 < HID; h2++) {
    float ta = t3a[(size_t)pix * HID + h2];
    float tb = t3b[(size_t)pix * HID + h2];
    float tc = t3c[(size_t)pix * HID + h2];
    sa.x += ta * w2a[(c + 0) * HID + h2]; sa.y += ta * w2a[(c + 1) * HID + h2];
    sa.z += ta * w2a[(c + 2) * HID + h2]; sa.w += ta * w2a[(c + 3) * HID + h2];
    sb.x += tb * w2b[(c + 0) * HID + h2]; sb.y += tb * w2b[(c + 1) * HID + h2];
    sb.z += tb * w2b[(c + 2) * HID + h2]; sb.w += tb * w2b[(c + 3) * HID + h2];
    sc.x += tc * w2c[(c + 0) * HID + h2]; sc.y += tc * w2c[(c + 1) * HID + h2];
    sc.z += tc * w2c[(c + 2) * HID + h2]; sc.w += tc * w2c[(c + 3) * HID + h2];
  }
  float g0 = gv[b * 3 + 0], g1 = gv[b * 3 + 1], g2 = gv[b * 3 + 2], m0 = ms[0];
  float* ap = A + (size_t)pix * CC + c;
  float4 av = *(const float4*)ap;
  av.x += m0 * (g0 * sa.x + g1 * sb.x + g2 * sc.x);
  av.y += m0 * (g0 * sa.y + g1 * sb.y + g2 * sc.y);
  av.z += m0 * (g0 * sa.z + g1 * sb.z + g2 * sc.z);
  av.w += m0 * (g0 * sa.w + g1 * sb.w + g2 * sc.w);
  *(float4*)ap = av;
}

// ---------------- Bias table (attn C-fragment order: [h][n>>2][m][n&3]) ----
__global__ __launch_bounds__(256) void bias_kernel(const int* __restrict__ rpi,
    const float* __restrict__ rpb, float* __restrict__ biasT) {
  int idx = blockIdx.x * 256 + threadIdx.x;
  int h = idx >> 16, nm = idx & 65535;
  int n = nm >> 8, m = nm & 255;
  biasT[(h << 16) + ((n >> 2) << 10) + (m << 2) + (n & 3)] = rpb[rpi[nm] * HEADS + h];
}

// ---------------- Windowed attention v5: V-in-registers, calibrated VGPR cap ----------
// Identical structure to v3/v4. ONLY change: __launch_bounds__(256, 2).
// Empirical mapping on this toolchain: arg 4 -> 64-VGPR cap (spilled ~50),
// arg 3 -> 84-VGPR cap (spilled ~25). Live set is ~110 VGPRs, so arg 2 -> 128 cap
// fits without spill while still allowing 4 waves/SIMD = the 4 blocks/CU that
// LDS (40960 B) permits.
__device__ __forceinline__ int swz(int r, int c) { return r * 256 + (c ^ (r << 3)); }

__global__ __launch_bounds__(256, 2) void attn_kernel(const float* __restrict__ X,
    const float* __restrict__ biasT, float* __restrict__ O) {
  __shared__ __align__(16) unsigned short kb[256][16];   // K bf16 (8192 B)
  __shared__ __align__(16) unsigned short sS[4][4096];   // per-wave keys->P (32768 B)
  int tid = threadIdx.x;
  int wi = blockIdx.x, hh = blockIdx.y;
  int b = wi >> 8, wrem = wi & 255, wy = wrem >> 4, wx = wrem & 15;
  int lane = tid & 63, wv_ = tid >> 6, quad = lane >> 4, to = lane & 15;
  unsigned short* sw = &sS[wv_][0];

  // stage K (bf16) into kb, V (bf16) into this wave's sS scratch: vstage[d][lane]
  {
    int m = tid;
    int nm = (((wy << 4) + (m >> 4)) << 8) | ((wx << 4) + (m & 15));
    size_t xb = ((size_t)(b << 16) + nm) * 288 + hh * 16;
    float kr[16], vr[16];
    *(float4*)&kr[0]  = *(const float4*)(X + xb + 96);
    *(float4*)&kr[4]  = *(const float4*)(X + xb + 100);
    *(float4*)&kr[8]  = *(const float4*)(X + xb + 104);
    *(float4*)&kr[12] = *(const float4*)(X + xb + 108);
    *(float4*)&vr[0]  = *(const float4*)(X + xb + 192);
    *(float4*)&vr[4]  = *(const float4*)(X + xb + 196);
    *(float4*)&vr[8]  = *(const float4*)(X + xb + 200);
    *(float4*)&vr[12] = *(const float4*)(X + xb + 204);
    unsigned u_[8];
    #pragma unroll
    for (int i = 0; i < 8; i++)
      u_[i] = (unsigned)bf16r(kr[2 * i]) | ((unsigned)bf16r(kr[2 * i + 1]) << 16);
    *(uint4*)&kb[m][0] = make_uint4(u_[0], u_[1], u_[2], u_[3]);
    *(uint4*)&kb[m][8] = make_uint4(u_[4], u_[5], u_[6], u_[7]);
    #pragma unroll
    for (int d = 0; d < 16; d++) sw[d * 64 + lane] = bf16r(vr[d]);
  }

  // Q fragment direct from global (A-operand: row=to, k=quad*8..+7; quads 2,3 zero)
  auto load_q = [&](int ch) -> v8s {
    v8s af = {0, 0, 0, 0, 0, 0, 0, 0};
    if (quad < 2) {
      int nq = (((wy << 4) + ch) << 8) | ((wx << 4) + to);
      const float* qp = X + ((size_t)(b << 16) + nq) * 288 + hh * 16 + quad * 8;
      float4 f0 = *(const float4*)qp;
      float4 f1 = *(const float4*)(qp + 4);
      uint4 u;
      u.x = (unsigned)bf16r(f0.x * 0.25f) | ((unsigned)bf16r(f0.y * 0.25f) << 16);
      u.y = (unsigned)bf16r(f0.z * 0.25f) | ((unsigned)bf16r(f0.w * 0.25f) << 16);
      u.z = (unsigned)bf16r(f1.x * 0.25f) | ((unsigned)bf16r(f1.y * 0.25f) << 16);
      u.w = (unsigned)bf16r(f1.z * 0.25f) | ((unsigned)bf16r(f1.w * 0.25f) << 16);
      af = *(v8s*)&u;
    }
    return af;
  };

  v8s afc = load_q(wv_ * 4);
  __syncthreads();   // B0: kb + V-stage ready

  // pull V into registers: vreg[kc] = V[kc*32+quad*8+j][to], j=0..7
  v8s vreg[8];
  #pragma unroll
  for (int kc = 0; kc < 8; kc++)
    vreg[kc] = *(const v8s*)&sS[kc >> 1][to * 64 + (kc & 1) * 32 + quad * 8];
  __syncthreads();   // B1: V reads done; sS free for keys/P. No barriers after this.

  #pragma unroll 1
  for (int j = 0; j < 4; j++) {
    int ch = wv_ * 4 + j;
    int r0 = ch * 16;
    // O (lepe) prefetch: output rows quad*4+rg, col to
    int n_o = (((wy << 4) + ch) << 8) | ((wx << 4) + (quad << 2));
    size_t ob = ((size_t)(b << 16) + n_o) * CC + hh * 16 + to;
    float oc0 = O[ob], oc1 = O[ob + 96], oc2 = O[ob + 192], oc3 = O[ob + 288];
    // ---- S = Q K^T + bias via MFMA; store top-16 bits to private LDS ----
    #pragma unroll
    for (int t = 0; t < 16; t++) {
      v8s bfr = {0, 0, 0, 0, 0, 0, 0, 0};
      if (quad < 2) bfr = *(const v8s*)&kb[t * 16 + to][quad * 8];
      float4 bv = *(const float4*)(biasT + ((size_t)hh << 16) +
                                   (size_t)(((r0 >> 2) + quad) << 10) + ((t * 16 + to) << 2));
      v4f cf;
      cf[0] = bv.x; cf[1] = bv.y; cf[2] = bv.z; cf[3] = bv.w;
      cf = __builtin_amdgcn_mfma_f32_16x16x32_bf16(afc, bfr, cf, 0, 0, 0);
      #pragma unroll
      for (int rg = 0; rg < 4; rg++)
        sw[swz(quad * 4 + rg, t * 16 + to)] = (unsigned short)(__float_as_uint(cf[rg]) >> 16);
    }
    // prefetch next chunk's Q (hidden under top-k)
    if (j < 3) afc = load_q(ch + 1);
    // ---- softmax + exact top-64 on 16-bit keys, 4 rows per group ----
    #pragma unroll 1
    for (int g = 0; g < 4; g++) {
      float ex_[4][4], inv_[4];
      unsigned uk[4][4], cand[4];
      int hb[4]; bool done[4];
      #pragma unroll
      for (int qr = 0; qr < 4; qr++) {
        int r = g * 4 + qr;
        unsigned h0 = sw[swz(r, lane)], h1 = sw[swz(r, 64 + lane)];
        unsigned h2 = sw[swz(r, 128 + lane)], h3 = sw[swz(r, 192 + lane)];
        float x0 = __uint_as_float(h0 << 16), x1 = __uint_as_float(h1 << 16);
        float x2 = __uint_as_float(h2 << 16), x3 = __uint_as_float(h3 << 16);
        float mx = fmaxf(fmaxf(x0, x1), fmaxf(x2, x3));
        #pragma unroll
        for (int off = 32; off; off >>= 1) mx = fmaxf(mx, __shfl_xor(mx, off));
        float e0 = __expf(x0 - mx), e1 = __expf(x1 - mx), e2 = __expf(x2 - mx), e3 = __expf(x3 - mx);
        float sm = e0 + e1 + e2 + e3;
        #pragma unroll
        for (int off = 32; off; off >>= 1) sm += __shfl_xor(sm, off);
        inv_[qr] = 1.0f / sm;
        ex_[qr][0] = e0; ex_[qr][1] = e1; ex_[qr][2] = e2; ex_[qr][3] = e3;
        unsigned u0 = (h0 & 0x8000u) ? (h0 ^ 0xFFFFu) : (h0 | 0x8000u);
        unsigned u1 = (h1 & 0x8000u) ? (h1 ^ 0xFFFFu) : (h1 | 0x8000u);
        unsigned u2 = (h2 & 0x8000u) ? (h2 ^ 0xFFFFu) : (h2 | 0x8000u);
        unsigned u3 = (h3 & 0x8000u) ? (h3 ^ 0xFFFFu) : (h3 | 0x8000u);
        uk[qr][0] = u0; uk[qr][1] = u1; uk[qr][2] = u2; uk[qr][3] = u3;
        unsigned ad = u0 & u1 & u2 & u3;
        unsigned orr = u0 | u1 | u2 | u3;
        #pragma unroll
        for (int off = 32; off; off >>= 1) {
          ad &= __shfl_xor(ad, off);
          orr |= __shfl_xor(orr, off);
        }
        unsigned diff = ad ^ orr;
        hb[qr] = diff ? (31 - __builtin_clz(diff)) : -1;
        unsigned lowmask = (hb[qr] < 0) ? 0u : ((1u << (hb[qr] + 1)) - 1u);
        cand[qr] = ad & ~lowmask;
        done[qr] = (hb[qr] < 0);
      }
      int hbmax = max(max(hb[0], hb[1]), max(hb[2], hb[3]));
      for (int bit = hbmax; bit >= 0; --bit) {
        if (done[0] && done[1] && done[2] && done[3]) break;
        #pragma unroll
        for (int qr = 0; qr < 4; qr++) {
          if (done[qr] || bit > hb[qr]) continue;
          unsigned t = cand[qr] | (1u << bit);
          int cnt = __popcll(__ballot(uk[qr][0] >= t)) + __popcll(__ballot(uk[qr][1] >= t)) +
                    __popcll(__ballot(uk[qr][2] >= t)) + __popcll(__ballot(uk[qr][3] >= t));
          if (cnt >= TOPK) { cand[qr] = t; if (cnt == TOPK) done[qr] = true; }
        }
      }
      #pragma unroll
      for (int qr = 0; qr < 4; qr++) {
        int r = g * 4 + qr;
        unsigned c_ = cand[qr];
        int gcnt = __popcll(__ballot(uk[qr][0] > c_)) + __popcll(__ballot(uk[qr][1] > c_)) +
                   __popcll(__ballot(uk[qr][2] > c_)) + __popcll(__ballot(uk[qr][3] > c_));
        int need = TOPK - gcnt;
        unsigned long long q0 = __ballot(uk[qr][0] == c_), q1 = __ballot(uk[qr][1] == c_);
        unsigned long long q2 = __ballot(uk[qr][2] == c_), q3 = __ballot(uk[qr][3] == c_);
        unsigned long long lt = ((unsigned long long)1 << lane) - 1ull;
        int p0c = __popcll(q0 & lt);
        int p1c = __popcll(q0) + __popcll(q1 & lt);
        int p2c = __popcll(q0) + __popcll(q1) + __popcll(q2 & lt);
        int p3c = __popcll(q0) + __popcll(q1) + __popcll(q2) + __popcll(q3 & lt);
        float iv = inv_[qr];
        sw[swz(r, lane)]       = (uk[qr][0] > c_ || (uk[qr][0] == c_ && p0c < need)) ? bf16r(ex_[qr][0] * iv) : (unsigned short)0;
        sw[swz(r, 64 + lane)]  = (uk[qr][1] > c_ || (uk[qr][1] == c_ && p1c < need)) ? bf16r(ex_[qr][1] * iv) : (unsigned short)0;
        sw[swz(r, 128 + lane)] = (uk[qr][2] > c_ || (uk[qr][2] == c_ && p2c < need)) ? bf16r(ex_[qr][2] * iv) : (unsigned short)0;
        sw[swz(r, 192 + lane)] = (uk[qr][3] > c_ || (uk[qr][3] == c_ && p3c < need)) ? bf16r(ex_[qr][3] * iv) : (unsigned short)0;
      }
    }
    // ---- AV via MFMA: full K=256 in f32 registers, V from vreg ----
    v4f acc = {0.f, 0.f, 0.f, 0.f};
    #pragma unroll
    for (int kc = 0; kc < 8; kc++) {
      v8s paf = *(const v8s*)&sw[swz(to, kc * 32 + quad * 8)];
      acc = __builtin_amdgcn_mfma_f32_16x16x32_bf16(paf, vreg[kc], acc, 0, 0, 0);
    }
    O[ob]       = oc0 + acc[0];
    O[ob + 96]  = oc1 + acc[1];
    O[ob + 192] = oc2 + acc[2];
    O[ob + 288] = oc3 + acc[3];
  }
}

extern "C" void kernel_launch(void* const* d_in, const int* in_sizes, int n_in,
                              void* d_out, int out_size, void* d_ws, size_t ws_size,
                              hipStream_t stream) {
  (void)in_sizes; (void)n_in; (void)out_size; (void)ws_size;
  const float* x     = (const float*)d_in[0];
  const float* n1_g  = (const float*)d_in[1];
  const float* n1_b  = (const float*)d_in[2];
  const float* n2_g  = (const float*)d_in[3];
  const float* n2_b  = (const float*)d_in[4];
  const float* g_w1  = (const float*)d_in[5];
  const float* g_b1  = (const float*)d_in[6];
  const float* g_w2  = (const float*)d_in[7];
  const float* g_b2  = (const float*)d_in[8];
  const float* e_w1[3]  = {(const float*)d_in[9],  (const float*)d_in[16], (const float*)d_in[23]};
  const float* e_b1[3]  = {(const float*)d_in[10], (const float*)d_in[17], (const float*)d_in[24]};
  const float* e_pw[3]  = {(const float*)d_in[11], (const float*)d_in[18], (const float*)d_in[25]};
  const float* e_dw[3]  = {(const float*)d_in[12], (const float*)d_in[19], (const float*)d_in[26]};
  const float* e_dwb[3] = {(const float*)d_in[13], (const float*)d_in[20], (const float*)d_in[27]};
  const float* e_w2[3]  = {(const float*)d_in[14], (const float*)d_in[21], (const float*)d_in[28]};
  const float* e_b2[3]  = {(const float*)d_in[15], (const float*)d_in[22], (const float*)d_in[29]};
  const float* ms    = (const float*)d_in[30];
  const float* qkv_w = (const float*)d_in[31];
  const float* qkv_b = (const float*)d_in[32];
  const float* lepe_w = (const float*)d_in[33];
  const float* lepe_b = (const float*)d_in[34];
  const float* rpb   = (const float*)d_in[35];
  const float* proj_w = (const float*)d_in[36];
  const float* proj_b = (const float*)d_in[37];
  const float* fc1_w = (const float*)d_in[38];
  const float* fc1_b = (const float*)d_in[39];
  const float* ffn_dw = (const float*)d_in[40];
  const float* ffn_db = (const float*)d_in[41];
  const float* fc2_w = (const float*)d_in[42];
  const float* fc2_b = (const float*)d_in[43];
  const int*   rpi   = (const int*)d_in[44];
  float* out = (float*)d_out;

  // Arena: 384 floats/token + small tail
  const size_t M = MTOK;
  float* ws = (float*)d_ws;
  float* A   = ws;
  float* t1  = ws + 96 * M;
  float* t2b = ws + 108 * M;
  float* t3[3] = { ws + 120 * M, ws + 132 * M, ws + 144 * M };
  float* X   = ws + 96 * M;            // stride 288, spans [96M, 384M)
  float* T   = ws + 192 * M;           // stride 192
  float* T2  = ws;                     // stride 192
  float* O   = A;
  float* S2  = out;                    // d_out as scratch for shortcut+proj
  float* biasT = out;                  // d_out head hosts biasT (dead before step 8)
  float* pooled = ws + 384 * M;        // 192 floats
  float* gv = pooled + 192;            // 6 floats

  // 0. bias table
  bias_kernel<<<HEADS * NTOK / 256, 256, 0, stream>>>(rpi, rpb, biasT);
  // 1. LN1
  ln_kernel<<<M / 4, 256, 0, stream>>>(x, n1_g, n1_b, A);
  // 2. gate
  hipMemsetAsync(pooled, 0, 256 * sizeof(float), stream);
  pool_kernel<<<dim3(128, 2), 128, 0, stream>>>(A, pooled);
  gate_kernel<<<1, 64, 0, stream>>>(pooled, g_w1, g_b1, g_w2, g_b2, gv);
  // 3. experts: w1(MFMA)+lrelu -> pw(vector) -> dwconv+lrelu
  for (int i = 0; i < 3; i++) {
    mgemm_kernel<96, 12, 1, false, true><<<dim3(1, 1024), 256, 0, stream>>>(
        A, e_w1[i], e_b1[i], nullptr, t1, 12, 0);
    gemm_kernel<12, 12, 12, 0, false, false><<<dim3(2048, 1), 256, 0, stream>>>(
        t1, e_pw[i], nullptr, nullptr, t2b, 12, 0);
    if (i == 0)
      dwconv_kernel<3, 12, 1, false><<<M * 3 / 256, 256, 0, stream>>>(t2b, e_dw[0], e_dwb[0], nullptr, t3[0], 12, 12, 0);
    else if (i == 1)
      dwconv_kernel<5, 12, 1, false><<<M * 3 / 256, 256, 0, stream>>>(t2b, e_dw[1], e_dwb[1], nullptr, t3[1], 12, 12, 0);
    else
      dwconv_kernel<7, 12, 1, false><<<M * 3 / 256, 256, 0, stream>>>(t2b, e_dw[2], e_dwb[2], nullptr, t3[2], 12, 12, 0);
  }
  // 4. combine -> y2 (in place in A)
  moe_combine_kernel<<<M * 24 / 256, 256, 0, stream>>>(A,
      t3[0], t3[1], t3[2], e_w2[0], e_w2[1], e_w2[2], e_b2[0], e_b2[1], e_b2[2], gv, ms);
  // 5. qkv (MFMA)
  mgemm_kernel<96, 288, 0, false, true><<<dim3(5, 1024), 256, 0, stream>>>(
      A, qkv_w, qkv_b, nullptr, X, 288, 0);
  // 6. lepe -> O (aliases A)
  dwconv4_kernel<5, 96, 2, false><<<M * 6 / 256, 256, 0, stream>>>(X + 192, lepe_w, lepe_b, nullptr, O, 288, 96, 0);
  // 7. attention: O = lepe + attn_s @ V
  attn_kernel<<<dim3(512, 6), 256, 0, stream>>>(X, biasT, O);
  // 8. proj + shortcut -> S2 (= d_out)
  mgemm_kernel<96, 96, 0, true, true><<<dim3(2, 1024), 256, 0, stream>>>(
      O, proj_w, proj_b, x, S2, 96, 96);
  // 9. LN2 -> A
  ln_kernel<<<M / 4, 256, 0, stream>>>(S2, n2_g, n2_b, A);
  // 10. fc1 + gelu (MFMA) -> T
  mgemm_kernel<96, 192, 2, false, true><<<dim3(3, 1024), 256, 0, stream>>>(
      A, fc1_w, fc1_b, nullptr, T, 192, 0);
  // 11. conv-FFN: T2 = T + gelu(dwconv5(T))
  dwconv4_kernel<5, 192, 2, true><<<M * 12 / 256, 256, 0, stream>>>(T, ffn_dw, ffn_db, T, T2, 192, 192, 192);
  // 12. fc2 + residual (MFMA) -> out
  mgemm_kernel<192, 96, 0, true, true><<<dim3(2, 1024), 256, 0, stream>>>(
      T2, fc2_w, fc2_b, S2, out, 96, 96);
}

// Round 6
// 1705.048 us; speedup vs baseline: 1.2439x; 1.2439x over previous
//
#include <hip/hip_runtime.h>
#include <cstdint>

// Shapes
#define BB 2
#define HH_ 256
#define WW_ 256
#define CC 96
#define NTOK 65536           // H*W
#define MTOK 131072          // B*N
#define HEADS 6
#define WS 16
#define WSQ 256
#define HEAD_D 16
#define TOPK 64
#define HID 12
#define MLP_ 192

typedef short v8s __attribute__((ext_vector_type(8)));
typedef float v4f __attribute__((ext_vector_type(4)));

__device__ __forceinline__ float gelu_f(float v) {
  return 0.5f * v * (1.0f + erff(v * 0.70710678118654752440f));
}
__device__ __forceinline__ float lrelu_f(float v) { return v >= 0.0f ? v : 0.2f * v; }
__device__ __forceinline__ unsigned short bf16r(float f) {
  unsigned u = __float_as_uint(f);
  unsigned r = u + 0x7fffu + ((u >> 16) & 1u);
  return (unsigned short)(r >> 16);
}
__device__ __forceinline__ float bf16d(unsigned short h) {
  return __uint_as_float(((unsigned)h) << 16);
}

// ---------------- LayerNorm over C=96: one wave per token ----------------
__global__ __launch_bounds__(256) void ln_kernel(const float* __restrict__ in,
    const float* __restrict__ gam, const float* __restrict__ bet, float* __restrict__ out) {
  int wid = blockIdx.x * 4 + (threadIdx.x >> 6);
  int lane = threadIdx.x & 63;
  const float* row = in + (size_t)wid * CC;
  float v0 = row[lane];
  float v1 = (lane < 32) ? row[64 + lane] : 0.0f;
  float s = v0 + v1;
  #pragma unroll
  for (int off = 32; off; off >>= 1) s += __shfl_xor(s, off);
  float mean = s * (1.0f / 96.0f);
  float d0 = v0 - mean;
  float d1 = (lane < 32) ? (v1 - mean) : 0.0f;
  float q = d0 * d0 + d1 * d1;
  #pragma unroll
  for (int off = 32; off; off >>= 1) q += __shfl_xor(q, off);
  float r = rsqrtf(q * (1.0f / 96.0f) + 1e-5f);
  float* orow = out + (size_t)wid * CC;
  orow[lane] = d0 * r * gam[lane] + bet[lane];
  if (lane < 32) orow[64 + lane] = d1 * r * gam[64 + lane] + bet[64 + lane];
}

// ---------------- Global average pool ----------------
__global__ __launch_bounds__(128) void pool_kernel(const float* __restrict__ A, float* __restrict__ pooled) {
  int c = threadIdx.x;
  if (c >= CC) return;
  int b = blockIdx.y;
  int t0 = blockIdx.x * 512;
  const float* base = A + ((size_t)b * NTOK + t0) * CC + c;
  float acc = 0.0f;
  #pragma unroll 8
  for (int t = 0; t < 512; t++) acc += base[(size_t)t * CC];
  atomicAdd(&pooled[b * CC + c], acc);
}

// ---------------- Gate MLP ----------------
__global__ __launch_bounds__(64) void gate_kernel(const float* __restrict__ pooled,
    const float* __restrict__ w1, const float* __restrict__ b1,
    const float* __restrict__ w2, const float* __restrict__ b2, float* __restrict__ gv) {
  __shared__ float hb[BB][HID];
  __shared__ float lb[BB][3];
  int tid = threadIdx.x;
  if (tid < BB * HID) {
    int b = tid / HID, o = tid % HID;
    float s = b1[o];
    for (int c = 0; c < CC; c++) s += (pooled[b * CC + c] * (1.0f / 65536.0f)) * w1[o * CC + c];
    hb[b][o] = fmaxf(s, 0.0f);
  }
  __syncthreads();
  if (tid < BB * 3) {
    int b = tid / 3, j = tid % 3;
    float s = b2[j];
    for (int o = 0; o < HID; o++) s += hb[b][o] * w2[j * HID + o];
    lb[b][j] = s;
  }
  __syncthreads();
  if (tid < BB) {
    float m = fmaxf(lb[tid][0], fmaxf(lb[tid][1], lb[tid][2]));
    float e0 = __expf(lb[tid][0] - m), e1 = __expf(lb[tid][1] - m), e2 = __expf(lb[tid][2] - m);
    float inv = 1.0f / (e0 + e1 + e2);
    gv[tid * 3 + 0] = e0 * inv; gv[tid * 3 + 1] = e1 * inv; gv[tid * 3 + 2] = e2 * inv;
  }
}

// ---------------- MFMA GEMM: out[p,o] = act(sum_c A[p,c]*W[o,c] + b[o]) (+resid) -------
template <int K, int NO, int ACT, bool RESID, bool HASB>
__global__ __launch_bounds__(256, 4) void mgemm_kernel(const float* __restrict__ A,
    const float* __restrict__ W, const float* __restrict__ bias,
    const float* __restrict__ resid, float* __restrict__ out, int ostride, int rstride) {
  __shared__ __align__(16) unsigned short al[128][104];  // stride 52 dw == 4 mod 8
  __shared__ __align__(16) unsigned short wl[64][104];
  int tid = threadIdx.x;
  int lane = tid & 63, wv = tid >> 6, quad = lane >> 4, to = lane & 15;
  int o0 = blockIdx.x * 64, p0 = blockIdx.y * 128;
  v4f acc[2][4];
  #pragma unroll
  for (int ni = 0; ni < 4; ni++) {
    float bv = 0.0f;
    if (HASB) { int o = o0 + ni * 16 + to; if (o < NO) bv = bias[o]; }
    #pragma unroll
    for (int mi = 0; mi < 2; mi++) acc[mi][ni] = (v4f){bv, bv, bv, bv};
  }
  for (int kc = 0; kc < K; kc += 96) {
    __syncthreads();
    {
      int r = tid & 127, half = tid >> 7;
      const float* ap = A + (size_t)(p0 + r) * K + kc + half * 48;
      #pragma unroll
      for (int g = 0; g < 3; g++) {
        float4 f0 = *(const float4*)(ap + g * 16);
        float4 f1 = *(const float4*)(ap + g * 16 + 4);
        float4 f2 = *(const float4*)(ap + g * 16 + 8);
        float4 f3 = *(const float4*)(ap + g * 16 + 12);
        uint4 u, v;
        u.x = (unsigned)bf16r(f0.x) | ((unsigned)bf16r(f0.y) << 16);
        u.y = (unsigned)bf16r(f0.z) | ((unsigned)bf16r(f0.w) << 16);
        u.z = (unsigned)bf16r(f1.x) | ((unsigned)bf16r(f1.y) << 16);
        u.w = (unsigned)bf16r(f1.z) | ((unsigned)bf16r(f1.w) << 16);
        v.x = (unsigned)bf16r(f2.x) | ((unsigned)bf16r(f2.y) << 16);
        v.y = (unsigned)bf16r(f2.z) | ((unsigned)bf16r(f2.w) << 16);
        v.z = (unsigned)bf16r(f3.x) | ((unsigned)bf16r(f3.y) << 16);
        v.w = (unsigned)bf16r(f3.z) | ((unsigned)bf16r(f3.w) << 16);
        *(uint4*)&al[r][half * 48 + g * 16] = u;
        *(uint4*)&al[r][half * 48 + g * 16 + 8] = v;
      }
    }
    {
      int r = tid & 63, q = tid >> 6;
      int o = o0 + r;
      if (o < NO) {
        const float* wp = W + (size_t)o * K + kc + q * 24;
        #pragma unroll
        for (int g = 0; g < 3; g++) {
          float4 f0 = *(const float4*)(wp + g * 8);
          float4 f1 = *(const float4*)(wp + g * 8 + 4);
          uint4 u;
          u.x = (unsigned)bf16r(f0.x) | ((unsigned)bf16r(f0.y) << 16);
          u.y = (unsigned)bf16r(f0.z) | ((unsigned)bf16r(f0.w) << 16);
          u.z = (unsigned)bf16r(f1.x) | ((unsigned)bf16r(f1.y) << 16);
          u.w = (unsigned)bf16r(f1.z) | ((unsigned)bf16r(f1.w) << 16);
          *(uint4*)&wl[r][q * 24 + g * 8] = u;
        }
      } else {
        uint4 z = make_uint4(0, 0, 0, 0);
        #pragma unroll
        for (int g = 0; g < 3; g++) *(uint4*)&wl[r][q * 24 + g * 8] = z;
      }
    }
    __syncthreads();
    #pragma unroll
    for (int ks = 0; ks < 3; ks++) {
      v8s af[2], bfr[4];
      #pragma unroll
      for (int mi = 0; mi < 2; mi++)
        af[mi] = *(const v8s*)&al[wv * 32 + mi * 16 + to][ks * 32 + quad * 8];
      #pragma unroll
      for (int ni = 0; ni < 4; ni++)
        bfr[ni] = *(const v8s*)&wl[ni * 16 + to][ks * 32 + quad * 8];
      #pragma unroll
      for (int mi = 0; mi < 2; mi++)
        #pragma unroll
        for (int ni = 0; ni < 4; ni++)
          acc[mi][ni] = __builtin_amdgcn_mfma_f32_16x16x32_bf16(af[mi], bfr[ni], acc[mi][ni], 0, 0, 0);
    }
  }
  #pragma unroll
  for (int mi = 0; mi < 2; mi++)
    #pragma unroll
    for (int ni = 0; ni < 4; ni++) {
      int o = o0 + ni * 16 + to;
      if (o < NO) {
        #pragma unroll
        for (int rg = 0; rg < 4; rg++) {
          int p = p0 + wv * 32 + mi * 16 + quad * 4 + rg;
          float v = acc[mi][ni][rg];
          if (ACT == 1) v = lrelu_f(v);
          else if (ACT == 2) v = gelu_f(v);
          if (RESID) v += resid[(size_t)p * rstride + o];
          out[(size_t)p * ostride + o] = v;
        }
      }
    }
}

// ---------------- Vector GEMM (small K; used for 12x12 pw) ----------------
template <int K, int KC, int NO, int ACT, bool RESID, bool HASB>
__global__ __launch_bounds__(256) void gemm_kernel(const float* __restrict__ in,
    const float* __restrict__ w, const float* __restrict__ bias,
    const float* __restrict__ resid, float* __restrict__ out, int ostride, int rstride) {
  __shared__ __align__(16) float xs[64][KC + 4];
  __shared__ __align__(16) float ws[64][KC + 4];
  int tid = threadIdx.x;
  int p0 = blockIdx.x * 64;
  int o0 = blockIdx.y * 64;
  int to = tid & 15, tp = tid >> 4;
  float acc[4][4];
  #pragma unroll
  for (int j = 0; j < 4; j++) {
    float bv = 0.0f;
    if (HASB) { int o = o0 + to + 16 * j; if (o < NO) bv = bias[o]; }
    #pragma unroll
    for (int i = 0; i < 4; i++) acc[i][j] = bv;
  }
  for (int kc = 0; kc < K; kc += KC) {
    __syncthreads();
    for (int idx = tid; idx < 64 * (KC / 4); idx += 256) {
      int p = idx / (KC / 4), c4 = idx % (KC / 4);
      *(float4*)&xs[p][c4 * 4] = *(const float4*)&in[(size_t)(p0 + p) * K + kc + c4 * 4];
    }
    for (int idx = tid; idx < 64 * (KC / 4); idx += 256) {
      int r = idx / (KC / 4), c4 = idx % (KC / 4);
      int o = o0 + r;
      float4 v = make_float4(0.f, 0.f, 0.f, 0.f);
      if (o < NO) v = *(const float4*)&w[(size_t)o * K + kc + c4 * 4];
      *(float4*)&ws[r][c4 * 4] = v;
    }
    __syncthreads();
    #pragma unroll 4
    for (int cc = 0; cc < KC; cc += 4) {
      float4 xv[4], wv[4];
      #pragma unroll
      for (int i = 0; i < 4; i++) xv[i] = *(const float4*)&xs[tp + 16 * i][cc];
      #pragma unroll
      for (int j = 0; j < 4; j++) wv[j] = *(const float4*)&ws[to + 16 * j][cc];
      #pragma unroll
      for (int i = 0; i < 4; i++)
        #pragma unroll
        for (int j = 0; j < 4; j++)
          acc[i][j] += xv[i].x * wv[j].x + xv[i].y * wv[j].y + xv[i].z * wv[j].z + xv[i].w * wv[j].w;
    }
  }
  #pragma unroll
  for (int i = 0; i < 4; i++) {
    int p = p0 + tp + 16 * i;
    #pragma unroll
    for (int j = 0; j < 4; j++) {
      int o = o0 + to + 16 * j;
      if (o < NO) {
        float v = acc[i][j];
        if (ACT == 1) v = lrelu_f(v);
        else if (ACT == 2) v = gelu_f(v);
        if (RESID) v += resid[(size_t)p * rstride + o];
        out[(size_t)p * ostride + o] = v;
      }
    }
  }
}

// ---------------- Depthwise KxK conv (NHWC), float4 over channels ----------------
template <int KSZ, int CH, int ACT, bool RESID>
__global__ __launch_bounds__(256) void dwconv_kernel(const float* __restrict__ in,
    const float* __restrict__ wt, const float* __restrict__ wb,
    const float* __restrict__ resid, float* __restrict__ out,
    int istride, int ostride, int rstride) {
  constexpr int C4 = CH / 4;
  constexpr int K2 = KSZ * KSZ;
  int e = blockIdx.x * 256 + threadIdx.x;
  int c4 = e % C4;
  int pix = e / C4;
  int b = pix >> 16, n = pix & 65535, h = n >> 8, w = n & 255;
  const int P = (KSZ - 1) / 2;
  int c = c4 * 4;
  float4 acc = *(const float4*)(wb + c);
  #pragma unroll
  for (int ky = 0; ky < KSZ; ky++) {
    int hh = h + ky - P;
    if (hh < 0 || hh >= HH_) continue;
    #pragma unroll
    for (int kx = 0; kx < KSZ; kx++) {
      int ww = w + kx - P;
      if (ww < 0 || ww >= WW_) continue;
      float4 iv = *(const float4*)(in + ((size_t)(b << 16) + (hh << 8) + ww) * istride + c);
      int t = ky * KSZ + kx;
      acc.x += wt[(c + 0) * K2 + t] * iv.x;
      acc.y += wt[(c + 1) * K2 + t] * iv.y;
      acc.z += wt[(c + 2) * K2 + t] * iv.z;
      acc.w += wt[(c + 3) * K2 + t] * iv.w;
    }
  }
  if (ACT == 1) {
    acc.x = lrelu_f(acc.x); acc.y = lrelu_f(acc.y); acc.z = lrelu_f(acc.z); acc.w = lrelu_f(acc.w);
  } else if (ACT == 2) {
    acc.x = gelu_f(acc.x); acc.y = gelu_f(acc.y); acc.z = gelu_f(acc.z); acc.w = gelu_f(acc.w);
  }
  if (RESID) {
    float4 rv = *(const float4*)(resid + (size_t)pix * rstride + c);
    acc.x += rv.x; acc.y += rv.y; acc.z += rv.z; acc.w += rv.w;
  }
  *(float4*)(out + (size_t)pix * ostride + c) = acc;
}

// ---------------- Depthwise 4-pixel conv: register reuse along W ----------------
template <int KSZ, int CH, int ACT, bool RESID>
__global__ __launch_bounds__(256) void dwconv4_kernel(const float* __restrict__ in,
    const float* __restrict__ wt, const float* __restrict__ wb,
    const float* __restrict__ resid, float* __restrict__ out,
    int istride, int ostride, int rstride) {
  constexpr int C4 = CH / 4;
  constexpr int K2 = KSZ * KSZ;
  constexpr int P = (KSZ - 1) / 2;
  constexpr int NC = KSZ + 3;
  int e = blockIdx.x * 256 + threadIdx.x;
  int c4 = e % C4;
  int g = e / C4;                     // pixel-group: b*16384 + h*64 + w0/4
  int b = g >> 14, rem = g & 16383, h = rem >> 6, w0 = (rem & 63) << 2;
  int c = c4 * 4;
  float4 wbv = *(const float4*)(wb + c);
  float4 acc[4] = {wbv, wbv, wbv, wbv};
  #pragma unroll
  for (int ky = 0; ky < KSZ; ky++) {
    int hh = h + ky - P;
    if (hh < 0 || hh >= HH_) continue;
    const float* rowp = in + ((size_t)(b << 16) + (hh << 8)) * istride + c;
    float4 iv[NC];
    #pragma unroll
    for (int k = 0; k < NC; k++) {
      int ww = w0 - P + k;
      if (ww >= 0 && ww < WW_) iv[k] = *(const float4*)(rowp + (size_t)ww * istride);
      else iv[k] = make_float4(0.f, 0.f, 0.f, 0.f);
    }
    #pragma unroll
    for (int kx = 0; kx < KSZ; kx++) {
      int t = ky * KSZ + kx;
      float wt0 = wt[(c + 0) * K2 + t];
      float wt1 = wt[(c + 1) * K2 + t];
      float wt2 = wt[(c + 2) * K2 + t];
      float wt3 = wt[(c + 3) * K2 + t];
      #pragma unroll
      for (int px = 0; px < 4; px++) {
        acc[px].x += wt0 * iv[kx + px].x;
        acc[px].y += wt1 * iv[kx + px].y;
        acc[px].z += wt2 * iv[kx + px].z;
        acc[px].w += wt3 * iv[kx + px].w;
      }
    }
  }
  #pragma unroll
  for (int px = 0; px < 4; px++) {
    float4 a = acc[px];
    if (ACT == 1) {
      a.x = lrelu_f(a.x); a.y = lrelu_f(a.y); a.z = lrelu_f(a.z); a.w = lrelu_f(a.w);
    } else if (ACT == 2) {
      a.x = gelu_f(a.x); a.y = gelu_f(a.y); a.z = gelu_f(a.z); a.w = gelu_f(a.w);
    }
    size_t pix = (size_t)(b << 16) + (h << 8) + w0 + px;
    if (RESID) {
      float4 rv = *(const float4*)(resid + pix * rstride + c);
      a.x += rv.x; a.y += rv.y; a.z += rv.z; a.w += rv.w;
    }
    *(float4*)(out + pix * ostride + c) = a;
  }
}

// ---------------- MoE combine (float4 over channels) ----------------
__global__ __launch_bounds__(256) void moe_combine_kernel(float* __restrict__ A,
    const float* __restrict__ t3a, const float* __restrict__ t3b, const float* __restrict__ t3c,
    const float* __restrict__ w2a, const float* __restrict__ w2b, const float* __restrict__ w2c,
    const float* __restrict__ b2a, const float* __restrict__ b2b, const float* __restrict__ b2c,
    const float* __restrict__ gv, const float* __restrict__ ms) {
  int e4 = blockIdx.x * 256 + threadIdx.x;
  int c4 = e4 % (CC / 4), pix = e4 / (CC / 4), b = pix >> 16;
  int c = c4 * 4;
  float4 sa = *(const float4*)(b2a + c);
  float4 sb = *(const float4*)(b2b + c);
  float4 sc = *(const float4*)(b2c + c);
  #pragma unroll
  for (int h2 = 0; h2 < HID; h2++) {
    float ta = t3a[(size_t)pix * HID + h2];
    float tb = t3b[(size_t)pix * HID + h2];
    float tc = t3c[(size_t)pix * HID + h2];
    sa.x += ta * w2a[(c + 0) * HID + h2]; sa.y += ta * w2a[(c + 1) * HID + h2];
    sa.z += ta * w2a[(c + 2) * HID + h2]; sa.w += ta * w2a[(c + 3) * HID + h2];
    sb.x += tb * w2b[(c + 0) * HID + h2]; sb.y += tb * w2b[(c + 1) * HID + h2];
    sb.z += tb * w2b[(c + 2) * HID + h2]; sb.w += tb * w2b[(c + 3) * HID + h2];
    sc.x += tc * w2c[(c + 0) * HID + h2]; sc.y += tc * w2c[(c + 1) * HID + h2];
    sc.z += tc * w2c[(c + 2) * HID + h2]; sc.w += tc * w2c[(c + 3) * HID + h2];
  }
  float g0 = gv[b * 3 + 0], g1 = gv[b * 3 + 1], g2 = gv[b * 3 + 2], m0 = ms[0];
  float* ap = A + (size_t)pix * CC + c;
  float4 av = *(const float4*)ap;
  av.x += m0 * (g0 * sa.x + g1 * sb.x + g2 * sc.x);
  av.y += m0 * (g0 * sa.y + g1 * sb.y + g2 * sc.y);
  av.z += m0 * (g0 * sa.z + g1 * sb.z + g2 * sc.z);
  av.w += m0 * (g0 * sa.w + g1 * sb.w + g2 * sc.w);
  *(float4*)ap = av;
}

// ---------------- Bias table (attn C-fragment order: [h][n>>2][m][n&3]) ----
__global__ __launch_bounds__(256) void bias_kernel(const int* __restrict__ rpi,
    const float* __restrict__ rpb, float* __restrict__ biasT) {
  int idx = blockIdx.x * 256 + threadIdx.x;
  int h = idx >> 16, nm = idx & 65535;
  int n = nm >> 8, m = nm & 255;
  biasT[(h << 16) + ((n >> 2) << 10) + (m << 2) + (n & 3)] = rpb[rpi[nm] * HEADS + h];
}

// ---------------- Windowed attention v6: cooperative, 2 barriers/chunk ----------------
// Back to the proven cooperative structure (4 waves share each 16-row chunk; per-wave
// top-k state is 1/4 of the wave-private design -> ~70 VGPRs, no spill). Two overheads
// removed vs the 823us r1 kernel:
//  (1) Q staged via direct global fragment loads (kills qc LDS + BA barrier).
//  (2) AV done by ONE wave per chunk (round-robin i&3): full 16x16 tile, 8 MFMAs,
//      A = P rows from shared sS, B = vt; O read-modify-write by that wave only.
//      Kills pOut round-trip + B3 barrier. sS is double-buffered so AV(i) overlaps
//      S(i+1); barrier order guarantees AV(i) completes before sS[i&1] is rewritten
//      at chunk i+2 (the AV wave passes B1(i+1) only after finishing AV(i)).
// LDS = 8192(kb) + 8448(vt) + 2*8448(sS) = 33536 B -> 4 blocks/CU.
__global__ __launch_bounds__(256, 3) void attn_kernel(const float* __restrict__ X,
    const float* __restrict__ biasT, float* __restrict__ O) {
  __shared__ __align__(16) unsigned short kb[256][16];    // K bf16 (8192 B)
  __shared__ __align__(16) unsigned short vt[16][264];    // V^T bf16 (8448 B)
  __shared__ __align__(16) unsigned short sSb[2][16][264];// S keys -> P, double buffer
  int tid = threadIdx.x;
  int wi = blockIdx.x, hh = blockIdx.y;
  int b = wi >> 8, wrem = wi & 255, wy = wrem >> 4, wx = wrem & 15;
  int lane = tid & 63, wv_ = tid >> 6, quad = lane >> 4, to = lane & 15;

  // stage K (bf16) and V^T (bf16)
  {
    int m = tid;
    int nm = (((wy << 4) + (m >> 4)) << 8) | ((wx << 4) + (m & 15));
    size_t xb = ((size_t)(b << 16) + nm) * 288 + hh * 16;
    float kr[16], vr[16];
    *(float4*)&kr[0]  = *(const float4*)(X + xb + 96);
    *(float4*)&kr[4]  = *(const float4*)(X + xb + 100);
    *(float4*)&kr[8]  = *(const float4*)(X + xb + 104);
    *(float4*)&kr[12] = *(const float4*)(X + xb + 108);
    *(float4*)&vr[0]  = *(const float4*)(X + xb + 192);
    *(float4*)&vr[4]  = *(const float4*)(X + xb + 196);
    *(float4*)&vr[8]  = *(const float4*)(X + xb + 200);
    *(float4*)&vr[12] = *(const float4*)(X + xb + 204);
    unsigned u_[8];
    #pragma unroll
    for (int i = 0; i < 8; i++)
      u_[i] = (unsigned)bf16r(kr[2 * i]) | ((unsigned)bf16r(kr[2 * i + 1]) << 16);
    *(uint4*)&kb[m][0] = make_uint4(u_[0], u_[1], u_[2], u_[3]);
    *(uint4*)&kb[m][8] = make_uint4(u_[4], u_[5], u_[6], u_[7]);
    #pragma unroll
    for (int d = 0; d < 16; d++) vt[d][m] = bf16r(vr[d]);
  }

  // Q fragment direct from global (A-operand: row=to, k=quad*8..+7; quads 2,3 zero)
  auto load_q = [&](int ch) -> v8s {
    v8s af = {0, 0, 0, 0, 0, 0, 0, 0};
    if (quad < 2) {
      int nq = (((wy << 4) + ch) << 8) | ((wx << 4) + to);
      const float* qp = X + ((size_t)(b << 16) + nq) * 288 + hh * 16 + quad * 8;
      float4 f0 = *(const float4*)qp;
      float4 f1 = *(const float4*)(qp + 4);
      uint4 u;
      u.x = (unsigned)bf16r(f0.x * 0.25f) | ((unsigned)bf16r(f0.y * 0.25f) << 16);
      u.y = (unsigned)bf16r(f0.z * 0.25f) | ((unsigned)bf16r(f0.w * 0.25f) << 16);
      u.z = (unsigned)bf16r(f1.x * 0.25f) | ((unsigned)bf16r(f1.y * 0.25f) << 16);
      u.w = (unsigned)bf16r(f1.z * 0.25f) | ((unsigned)bf16r(f1.w * 0.25f) << 16);
      af = *(v8s*)&u;
    }
    return af;
  };

  v8s afc = load_q(0);
  __syncthreads();   // B0: kb/vt staged

  #pragma unroll 1
  for (int i = 0; i < 16; i++) {
    unsigned short (*sw)[264] = sSb[i & 1];
    int r0 = i * 16;
    bool avw = (wv_ == (i & 3));
    // AV wave prefetches O (lepe) for this chunk early (hidden under S + topk)
    size_t ob = 0;
    float oc0 = 0.f, oc1 = 0.f, oc2 = 0.f, oc3 = 0.f;
    if (avw) {
      int n_o = (((wy << 4) + i) << 8) | ((wx << 4) + (quad << 2));
      ob = ((size_t)(b << 16) + n_o) * CC + hh * 16 + to;
      oc0 = O[ob]; oc1 = O[ob + 96]; oc2 = O[ob + 192]; oc3 = O[ob + 288];
    }
    // ---- S = Q K^T + bias via MFMA; each wave covers 4 column-tiles ----
    #pragma unroll
    for (int t = 0; t < 4; t++) {
      int c0 = (wv_ * 4 + t) * 16;
      v8s bfr = {0, 0, 0, 0, 0, 0, 0, 0};
      if (quad < 2) bfr = *(const v8s*)&kb[c0 + to][quad * 8];
      float4 bv = *(const float4*)(biasT + ((size_t)hh << 16) +
                                   (size_t)(((r0 >> 2) + quad) << 10) + ((c0 + to) << 2));
      v4f cf;
      cf[0] = bv.x; cf[1] = bv.y; cf[2] = bv.z; cf[3] = bv.w;
      cf = __builtin_amdgcn_mfma_f32_16x16x32_bf16(afc, bfr, cf, 0, 0, 0);
      #pragma unroll
      for (int rg = 0; rg < 4; rg++)
        sw[quad * 4 + rg][c0 + to] = (unsigned short)(__float_as_uint(cf[rg]) >> 16);
    }
    // prefetch next chunk's Q (hidden under top-k)
    if (i < 15) afc = load_q(i + 1);
    __syncthreads();   // B1: keys ready
    // ---- softmax + exact top-64 on 16-bit keys (4 rows per wave) ----
    {
      float ex_[4][4], inv_[4];
      unsigned uk[4][4], cand[4];
      int hb[4]; bool done[4];
      #pragma unroll
      for (int qr = 0; qr < 4; qr++) {
        int r = wv_ * 4 + qr;
        unsigned h0 = sw[r][lane], h1 = sw[r][64 + lane];
        unsigned h2 = sw[r][128 + lane], h3 = sw[r][192 + lane];
        float x0 = __uint_as_float(h0 << 16), x1 = __uint_as_float(h1 << 16);
        float x2 = __uint_as_float(h2 << 16), x3 = __uint_as_float(h3 << 16);
        float mx = fmaxf(fmaxf(x0, x1), fmaxf(x2, x3));
        #pragma unroll
        for (int off = 32; off; off >>= 1) mx = fmaxf(mx, __shfl_xor(mx, off));
        float e0 = __expf(x0 - mx), e1 = __expf(x1 - mx), e2 = __expf(x2 - mx), e3 = __expf(x3 - mx);
        float sm = e0 + e1 + e2 + e3;
        #pragma unroll
        for (int off = 32; off; off >>= 1) sm += __shfl_xor(sm, off);
        inv_[qr] = 1.0f / sm;
        ex_[qr][0] = e0; ex_[qr][1] = e1; ex_[qr][2] = e2; ex_[qr][3] = e3;
        unsigned u0 = (h0 & 0x8000u) ? (h0 ^ 0xFFFFu) : (h0 | 0x8000u);
        unsigned u1 = (h1 & 0x8000u) ? (h1 ^ 0xFFFFu) : (h1 | 0x8000u);
        unsigned u2 = (h2 & 0x8000u) ? (h2 ^ 0xFFFFu) : (h2 | 0x8000u);
        unsigned u3 = (h3 & 0x8000u) ? (h3 ^ 0xFFFFu) : (h3 | 0x8000u);
        uk[qr][0] = u0; uk[qr][1] = u1; uk[qr][2] = u2; uk[qr][3] = u3;
        unsigned ad = u0 & u1 & u2 & u3;
        unsigned orr = u0 | u1 | u2 | u3;
        #pragma unroll
        for (int off = 32; off; off >>= 1) {
          ad &= __shfl_xor(ad, off);
          orr |= __shfl_xor(orr, off);
        }
        unsigned diff = ad ^ orr;
        hb[qr] = diff ? (31 - __builtin_clz(diff)) : -1;
        unsigned lowmask = (hb[qr] < 0) ? 0u : ((1u << (hb[qr] + 1)) - 1u);
        cand[qr] = ad & ~lowmask;
        done[qr] = (hb[qr] < 0);
      }
      int hbmax = max(max(hb[0], hb[1]), max(hb[2], hb[3]));
      for (int bit = hbmax; bit >= 0; --bit) {
        if (done[0] && done[1] && done[2] && done[3]) break;
        #pragma unroll
        for (int qr = 0; qr < 4; qr++) {
          if (done[qr] || bit > hb[qr]) continue;
          unsigned t = cand[qr] | (1u << bit);
          int cnt = __popcll(__ballot(uk[qr][0] >= t)) + __popcll(__ballot(uk[qr][1] >= t)) +
                    __popcll(__ballot(uk[qr][2] >= t)) + __popcll(__ballot(uk[qr][3] >= t));
          if (cnt >= TOPK) { cand[qr] = t; if (cnt == TOPK) done[qr] = true; }
        }
      }
      #pragma unroll
      for (int qr = 0; qr < 4; qr++) {
        int r = wv_ * 4 + qr;
        unsigned c_ = cand[qr];
        int gcnt = __popcll(__ballot(uk[qr][0] > c_)) + __popcll(__ballot(uk[qr][1] > c_)) +
                   __popcll(__ballot(uk[qr][2] > c_)) + __popcll(__ballot(uk[qr][3] > c_));
        int need = TOPK - gcnt;
        unsigned long long q0 = __ballot(uk[qr][0] == c_), q1 = __ballot(uk[qr][1] == c_);
        unsigned long long q2 = __ballot(uk[qr][2] == c_), q3 = __ballot(uk[qr][3] == c_);
        unsigned long long lt = ((unsigned long long)1 << lane) - 1ull;
        int p0c = __popcll(q0 & lt);
        int p1c = __popcll(q0) + __popcll(q1 & lt);
        int p2c = __popcll(q0) + __popcll(q1) + __popcll(q2 & lt);
        int p3c = __popcll(q0) + __popcll(q1) + __popcll(q2) + __popcll(q3 & lt);
        float iv = inv_[qr];
        sw[r][lane]       = (uk[qr][0] > c_ || (uk[qr][0] == c_ && p0c < need)) ? bf16r(ex_[qr][0] * iv) : (unsigned short)0;
        sw[r][64 + lane]  = (uk[qr][1] > c_ || (uk[qr][1] == c_ && p1c < need)) ? bf16r(ex_[qr][1] * iv) : (unsigned short)0;
        sw[r][128 + lane] = (uk[qr][2] > c_ || (uk[qr][2] == c_ && p2c < need)) ? bf16r(ex_[qr][2] * iv) : (unsigned short)0;
        sw[r][192 + lane] = (uk[qr][3] > c_ || (uk[qr][3] == c_ && p3c < need)) ? bf16r(ex_[qr][3] * iv) : (unsigned short)0;
      }
    }
    __syncthreads();   // B2: P ready
    // ---- AV by the round-robin wave: full 16x16 tile, K=256 via 8 MFMAs ----
    if (avw) {
      v4f acc = {0.f, 0.f, 0.f, 0.f};
      #pragma unroll
      for (int kc = 0; kc < 8; kc++) {
        v8s paf = *(const v8s*)&sw[to][kc * 32 + quad * 8];
        v8s vbf = *(const v8s*)&vt[to][kc * 32 + quad * 8];
        acc = __builtin_amdgcn_mfma_f32_16x16x32_bf16(paf, vbf, acc, 0, 0, 0);
      }
      O[ob]       = oc0 + acc[0];
      O[ob + 96]  = oc1 + acc[1];
      O[ob + 192] = oc2 + acc[2];
      O[ob + 288] = oc3 + acc[3];
    }
  }
}

extern "C" void kernel_launch(void* const* d_in, const int* in_sizes, int n_in,
                              void* d_out, int out_size, void* d_ws, size_t ws_size,
                              hipStream_t stream) {
  (void)in_sizes; (void)n_in; (void)out_size; (void)ws_size;
  const float* x     = (const float*)d_in[0];
  const float* n1_g  = (const float*)d_in[1];
  const float* n1_b  = (const float*)d_in[2];
  const float* n2_g  = (const float*)d_in[3];
  const float* n2_b  = (const float*)d_in[4];
  const float* g_w1  = (const float*)d_in[5];
  const float* g_b1  = (const float*)d_in[6];
  const float* g_w2  = (const float*)d_in[7];
  const float* g_b2  = (const float*)d_in[8];
  const float* e_w1[3]  = {(const float*)d_in[9],  (const float*)d_in[16], (const float*)d_in[23]};
  const float* e_b1[3]  = {(const float*)d_in[10], (const float*)d_in[17], (const float*)d_in[24]};
  const float* e_pw[3]  = {(const float*)d_in[11], (const float*)d_in[18], (const float*)d_in[25]};
  const float* e_dw[3]  = {(const float*)d_in[12], (const float*)d_in[19], (const float*)d_in[26]};
  const float* e_dwb[3] = {(const float*)d_in[13], (const float*)d_in[20], (const float*)d_in[27]};
  const float* e_w2[3]  = {(const float*)d_in[14], (const float*)d_in[21], (const float*)d_in[28]};
  const float* e_b2[3]  = {(const float*)d_in[15], (const float*)d_in[22], (const float*)d_in[29]};
  const float* ms    = (const float*)d_in[30];
  const float* qkv_w = (const float*)d_in[31];
  const float* qkv_b = (const float*)d_in[32];
  const float* lepe_w = (const float*)d_in[33];
  const float* lepe_b = (const float*)d_in[34];
  const float* rpb   = (const float*)d_in[35];
  const float* proj_w = (const float*)d_in[36];
  const float* proj_b = (const float*)d_in[37];
  const float* fc1_w = (const float*)d_in[38];
  const float* fc1_b = (const float*)d_in[39];
  const float* ffn_dw = (const float*)d_in[40];
  const float* ffn_db = (const float*)d_in[41];
  const float* fc2_w = (const float*)d_in[42];
  const float* fc2_b = (const float*)d_in[43];
  const int*   rpi   = (const int*)d_in[44];
  float* out = (float*)d_out;

  // Arena: 384 floats/token + small tail
  const size_t M = MTOK;
  float* ws = (float*)d_ws;
  float* A   = ws;
  float* t1  = ws + 96 * M;
  float* t2b = ws + 108 * M;
  float* t3[3] = { ws + 120 * M, ws + 132 * M, ws + 144 * M };
  float* X   = ws + 96 * M;            // stride 288, spans [96M, 384M)
  float* T   = ws + 192 * M;           // stride 192
  float* T2  = ws;                     // stride 192
  float* O   = A;
  float* S2  = out;                    // d_out as scratch for shortcut+proj
  float* biasT = out;                  // d_out head hosts biasT (dead before step 8)
  float* pooled = ws + 384 * M;        // 192 floats
  float* gv = pooled + 192;            // 6 floats

  // 0. bias table
  bias_kernel<<<HEADS * NTOK / 256, 256, 0, stream>>>(rpi, rpb, biasT);
  // 1. LN1
  ln_kernel<<<M / 4, 256, 0, stream>>>(x, n1_g, n1_b, A);
  // 2. gate
  hipMemsetAsync(pooled, 0, 256 * sizeof(float), stream);
  pool_kernel<<<dim3(128, 2), 128, 0, stream>>>(A, pooled);
  gate_kernel<<<1, 64, 0, stream>>>(pooled, g_w1, g_b1, g_w2, g_b2, gv);
  // 3. experts: w1(MFMA)+lrelu -> pw(vector) -> dwconv+lrelu
  for (int i = 0; i < 3; i++) {
    mgemm_kernel<96, 12, 1, false, true><<<dim3(1, 1024), 256, 0, stream>>>(
        A, e_w1[i], e_b1[i], nullptr, t1, 12, 0);
    gemm_kernel<12, 12, 12, 0, false, false><<<dim3(2048, 1), 256, 0, stream>>>(
        t1, e_pw[i], nullptr, nullptr, t2b, 12, 0);
    if (i == 0)
      dwconv_kernel<3, 12, 1, false><<<M * 3 / 256, 256, 0, stream>>>(t2b, e_dw[0], e_dwb[0], nullptr, t3[0], 12, 12, 0);
    else if (i == 1)
      dwconv_kernel<5, 12, 1, false><<<M * 3 / 256, 256, 0, stream>>>(t2b, e_dw[1], e_dwb[1], nullptr, t3[1], 12, 12, 0);
    else
      dwconv_kernel<7, 12, 1, false><<<M * 3 / 256, 256, 0, stream>>>(t2b, e_dw[2], e_dwb[2], nullptr, t3[2], 12, 12, 0);
  }
  // 4. combine -> y2 (in place in A)
  moe_combine_kernel<<<M * 24 / 256, 256, 0, stream>>>(A,
      t3[0], t3[1], t3[2], e_w2[0], e_w2[1], e_w2[2], e_b2[0], e_b2[1], e_b2[2], gv, ms);
  // 5. qkv (MFMA)
  mgemm_kernel<96, 288, 0, false, true><<<dim3(5, 1024), 256, 0, stream>>>(
      A, qkv_w, qkv_b, nullptr, X, 288, 0);
  // 6. lepe -> O (aliases A)
  dwconv4_kernel<5, 96, 2, false><<<M * 6 / 256, 256, 0, stream>>>(X + 192, lepe_w, lepe_b, nullptr, O, 288, 96, 0);
  // 7. attention: O = lepe + attn_s @ V
  attn_kernel<<<dim3(512, 6), 256, 0, stream>>>(X, biasT, O);
  // 8. proj + shortcut -> S2 (= d_out)
  mgemm_kernel<96, 96, 0, true, true><<<dim3(2, 1024), 256, 0, stream>>>(
      O, proj_w, proj_b, x, S2, 96, 96);
  // 9. LN2 -> A
  ln_kernel<<<M / 4, 256, 0, stream>>>(S2, n2_g, n2_b, A);
  // 10. fc1 + gelu (MFMA) -> T
  mgemm_kernel<96, 192, 2, false, true><<<dim3(3, 1024), 256, 0, stream>>>(
      A, fc1_w, fc1_b, nullptr, T, 192, 0);
  // 11. conv-FFN: T2 = T + gelu(dwconv5(T))
  dwconv4_kernel<5, 192, 2, true><<<M * 12 / 256, 256, 0, stream>>>(T, ffn_dw, ffn_db, T, T2, 192, 192, 192);
  // 12. fc2 + residual (MFMA) -> out
  mgemm_kernel<192, 96, 0, true, true><<<dim3(2, 1024), 256, 0, stream>>>(
      T2, fc2_w, fc2_b, S2, out, 96, 96);
}